// Round 7
// baseline (1016.395 us; speedup 1.0000x reference)
//
#include <hip/hip_runtime.h>
#include <hip/hip_fp16.h>

// Sinkhorn OT: n=m=4096, d=32, reg=0.1, 100 iterations, uniform marginals.
// R12 = R11 mailbox persistent kernel with the LDS staging hop DELETED.
// Index algebra: a wave's chain-c operand V[g0+c*64] is exactly mailbox
// entry (hlf*256 + c*64 + lane) -> each lane polls its own 4 tags and loads
// its own 4 entries DIRECTLY into the dot registers. Removes the staging
// write + staging barrier + LDS re-read from the per-half-pass critical path.
// Publish path parallelized: lanes 0-7 of wave 0 do the 8 fp32 divides
// (was 1 thread serial), pack via shfl, lane 0 stores data -> vmcnt(0) ->
// tag. Freeze history (16B/block, block-private) moved to lane-0 registers
// (removes 2 global RT loads from the odd-t publish path); freeze bit rides
// in the v-tag (bit31); break is uniform since every block's 16 waves
// collectively observe all 512 tags (8x coverage).
// Numerics bit-identical to R6..R11 (same dot order, same IEEE divides).
// Fallback: R6 per-iteration dispatch loop if cooperative launch fails.

#define NN 4096
#define MM 4096
#define DD 32
#define N_ITERS 100

static constexpr float INV_REG = 10.0f;
static constexpr float A_MARG  = 1.0f / 4096.0f;
static constexpr float B_MARG  = 1.0f / 4096.0f;

typedef _Float16 h2_t __attribute__((ext_vector_type(2)));
typedef unsigned u32v4 __attribute__((ext_vector_type(4)));

static __device__ __forceinline__ float dot2(unsigned a, unsigned b, float acc) {
#if __has_builtin(__builtin_amdgcn_fdot2)
    return __builtin_amdgcn_fdot2(__builtin_bit_cast(h2_t, a),
                                  __builtin_bit_cast(h2_t, b), acc, false);
#else
    float2 fa = __half22float2(*(const __half2*)&a);
    float2 fb = __half22float2(*(const __half2*)&b);
    acc = fmaf(fa.x, fb.x, acc);
    return fmaf(fa.y, fb.y, acc);
#endif
}

// Non-temporal 16B load (K^T streaming: no L2 allocation).
static __device__ __forceinline__ uint4 ld_nt_u4(const uint4* p) {
#if __has_builtin(__builtin_nontemporal_load)
    u32v4 r = __builtin_nontemporal_load((const u32v4*)p);
    uint4 o; o.x = r[0]; o.y = r[1]; o.z = r[2]; o.w = r[3];
    return o;
#else
    return *p;
#endif
}

static __device__ __forceinline__ unsigned ld_dev_u32(const unsigned* p) {
    return __hip_atomic_load(p, __ATOMIC_RELAXED, __HIP_MEMORY_SCOPE_AGENT);
}
static __device__ __forceinline__ void st_dev_u32(unsigned* p, unsigned v) {
    __hip_atomic_store(p, v, __ATOMIC_RELAXED, __HIP_MEMORY_SCOPE_AGENT);
}
static __device__ __forceinline__ unsigned short ld_dev_u16(const unsigned short* p) {
    return __hip_atomic_load(p, __ATOMIC_RELAXED, __HIP_MEMORY_SCOPE_AGENT);
}
static __device__ __forceinline__ void st_dev_u16(unsigned short* p, unsigned short v) {
    __hip_atomic_store(p, v, __ATOMIC_RELAXED, __HIP_MEMORY_SCOPE_AGENT);
}
static __device__ __forceinline__ unsigned long long ld_dev_u64(const unsigned long long* p) {
    return __hip_atomic_load(p, __ATOMIC_RELAXED, __HIP_MEMORY_SCOPE_AGENT);
}
static __device__ __forceinline__ void st_dev_u64(unsigned long long* p, unsigned long long v) {
    __hip_atomic_store(p, v, __ATOMIC_RELAXED, __HIP_MEMORY_SCOPE_AGENT);
}

// Coherent (L2-bypass) load of one 16B mailbox entry into a uint4.
static __device__ __forceinline__ uint4 ld_ent(const unsigned long long* md, int e) {
    unsigned long long d0 = ld_dev_u64(md + 2 * e);
    unsigned long long d1 = ld_dev_u64(md + 2 * e + 1);
    uint4 r;
    r.x = (unsigned)d0; r.y = (unsigned)(d0 >> 32);
    r.z = (unsigned)d1; r.w = (unsigned)(d1 >> 32);
    return r;
}

// ---------------------------------------------------------------------------
// Kh[i][j] = (half)exp(-||p_i - q_j||^2 / reg). prime!=0: v16=1/4096,
// conv=0, slot=1 (fallback path), mailbox tags zeroed.
// grid: (4096/256, 4096/16), block 256
// ---------------------------------------------------------------------------
__global__ void compute_K_half(const float* __restrict__ p, const float* __restrict__ q,
                               __half* __restrict__ Kh, __half* __restrict__ v16,
                               unsigned* __restrict__ conv, unsigned* __restrict__ slot,
                               unsigned* __restrict__ mtu, unsigned* __restrict__ mtv,
                               int prime) {
    const int tid = threadIdx.x;
    const int j   = blockIdx.x * 256 + tid;
    const int r0  = blockIdx.y * 16;

    if (prime && blockIdx.y == 0) {
        v16[j] = __float2half(B_MARG);
        if (blockIdx.x == 0) {
            if (tid == 0) { *conv = 0u; *slot = 1u; }
            mtu[tid] = 0u; mtu[tid + 256] = 0u;
            mtv[tid] = 0u; mtv[tid + 256] = 0u;
        }
    }

    float qv[DD];
    const float4* q4 = (const float4*)(q + (size_t)j * DD);
#pragma unroll
    for (int k = 0; k < DD / 4; ++k) {
        float4 t = q4[k];
        qv[4 * k + 0] = t.x; qv[4 * k + 1] = t.y;
        qv[4 * k + 2] = t.z; qv[4 * k + 3] = t.w;
    }

    __shared__ float ps[16 * DD];
    ps[tid]       = p[(size_t)r0 * DD + tid];
    ps[tid + 256] = p[(size_t)r0 * DD + tid + 256];
    __syncthreads();

#pragma unroll 4
    for (int ii = 0; ii < 16; ++ii) {
        float acc = 0.0f;
#pragma unroll
        for (int k = 0; k < DD; ++k) {
            float d = ps[ii * DD + k] - qv[k];
            acc = fmaf(d, d, acc);
        }
        Kh[(size_t)(r0 + ii) * MM + j] = __float2half(__expf(-acc * INV_REG));
    }
}

// ---------------------------------------------------------------------------
// Persistent kernel: all 100 iterations, mailbox-synced, zero LDS staging.
// 512 blocks x 1024 thr (16 waves), 2 waves per row, 4 fdot2 chains whose
// v/u operands are per-lane direct mailbox loads. Bit-identical accumulation
// order to R6..R11.
// ---------------------------------------------------------------------------
__global__ void __launch_bounds__(1024, 8)
sinkhorn_persist(const __half* __restrict__ Kh, const __half* __restrict__ KTh,
                 float* __restrict__ u32g, float* __restrict__ v32g,
                 unsigned* __restrict__ mtu, unsigned* __restrict__ mtv,
                 unsigned long long* __restrict__ mdu,
                 unsigned long long* __restrict__ mdv) {
    __shared__ float part[16];
    __shared__ unsigned fb_lds[16];
    const int tid  = threadIdx.x;
    const int lane = tid & 63;
    const int w    = tid >> 6;          // wave 0..15
    const int rib  = w >> 1;            // row-in-block 0..7
    const int hlf  = w & 1;             // half-row
    const int bid  = blockIdx.x;
    const int i    = bid * 8 + rib;
    const int g0   = hlf * 256 + lane;  // uint4 index into 512-uint4 row
    // chain-c operand = mailbox entry g0 + c*64 (per-lane)
    const int e0 = g0, e1 = g0 + 64, e2 = g0 + 128, e3 = g0 + 192;
    const uint4* __restrict__ MU = (const uint4*)(Kh  + (size_t)i * MM);
    const uint4* __restrict__ MV = (const uint4*)(KTh + (size_t)i * MM);

    // freeze history: block-private 16B, lives in lane0-of-wave0 registers.
    // init to all-ones (halves of a valid v are positive -> never equal).
    unsigned long long h0p = ~0ULL, h1p = ~0ULL;

    // prefetch u-half matrix rows for t=0
    uint4 k0 = MU[g0], k1 = MU[g0 + 64], k2 = MU[g0 + 128], k3 = MU[g0 + 192];

    for (int t = 0; t < N_ITERS; ++t) {
        // ===== u-half operands: v(t-1), per-lane direct mailbox loads =====
        uint4 va, vb, vc, vd;
        if (t == 0) {
            const unsigned dv2 =
                0x00010001u * (unsigned)__half_as_ushort(__float2half(B_MARG));
            va.x = va.y = va.z = va.w = dv2; vb = va; vc = va; vd = va;
        } else {
            const unsigned want = 2u * (unsigned)t;   // v(t-1) tag
            unsigned t0, t1, t2, t3;
            for (;;) {
                t0 = ld_dev_u32(mtv + e0); t1 = ld_dev_u32(mtv + e1);
                t2 = ld_dev_u32(mtv + e2); t3 = ld_dev_u32(mtv + e3);
                if (((t0 & 0x7fffffffu) == want) && ((t1 & 0x7fffffffu) == want) &&
                    ((t2 & 0x7fffffffu) == want) && ((t3 & 0x7fffffffu) == want))
                    break;
                __builtin_amdgcn_s_sleep(1);
            }
            asm volatile("" ::: "memory");   // keep data loads after the poll
            va = ld_ent(mdv, e0); vb = ld_ent(mdv, e1);
            vc = ld_ent(mdv, e2); vd = ld_ent(mdv, e3);
            const bool fz = __all(((t0 & t1 & t2 & t3) >> 31) != 0u);
            if (lane == 0) fb_lds[w] = fz ? 1u : 0u;
        }

        // ===== u-half compute: u = a / (Kh . v) =====
        {
            float x0 = 0.f, x1 = 0.f, x2 = 0.f, x3 = 0.f;
            x0 = dot2(k0.x, va.x, x0); x0 = dot2(k0.y, va.y, x0);
            x0 = dot2(k0.z, va.z, x0); x0 = dot2(k0.w, va.w, x0);
            x1 = dot2(k1.x, vb.x, x1); x1 = dot2(k1.y, vb.y, x1);
            x1 = dot2(k1.z, vb.z, x1); x1 = dot2(k1.w, vb.w, x1);
            x2 = dot2(k2.x, vc.x, x2); x2 = dot2(k2.y, vc.y, x2);
            x2 = dot2(k2.z, vc.z, x2); x2 = dot2(k2.w, vc.w, x2);
            x3 = dot2(k3.x, vd.x, x3); x3 = dot2(k3.y, vd.y, x3);
            x3 = dot2(k3.z, vd.z, x3); x3 = dot2(k3.w, vd.w, x3);
            float acc = (x0 + x1) + (x2 + x3);
#pragma unroll
            for (int off = 32; off > 0; off >>= 1) acc += __shfl_down(acc, off, 64);
            if (lane == 0) part[w] = acc;
        }
        // waves 1..15: prefetch v-half rows now (overlaps publish+poll)
        if (w != 0) {
            k0 = ld_nt_u4(MV + g0);       k1 = ld_nt_u4(MV + g0 + 64);
            k2 = ld_nt_u4(MV + g0 + 128); k3 = ld_nt_u4(MV + g0 + 192);
        }
        __syncthreads();
        if (t != 0 && (t & 1) == 0) {
            // frozen: v(t-1)==v(t-3) bitwise everywhere -> all remaining
            // iterations bit-identical; u32g/v32g already hold u,v(t-1).
            unsigned f = 1u;
#pragma unroll
            for (int q = 0; q < 16; ++q) f &= fb_lds[q];
            if (f) break;
        }
        if (w == 0) {   // publish u(t): parallel divides, shfl pack, lane0 tag
            unsigned hb = 0u;
            if (lane < 8) {
                float r = A_MARG / (part[2 * lane] + part[2 * lane + 1]);
                u32g[bid * 8 + lane] = r;
                hb = (unsigned)__half_as_ushort(__float2half(r));
            }
            const unsigned q0 = __shfl(hb, 0, 64), q1 = __shfl(hb, 1, 64);
            const unsigned q2 = __shfl(hb, 2, 64), q3 = __shfl(hb, 3, 64);
            const unsigned q4 = __shfl(hb, 4, 64), q5 = __shfl(hb, 5, 64);
            const unsigned q6 = __shfl(hb, 6, 64), q7 = __shfl(hb, 7, 64);
            if (lane == 0) {
                const unsigned long long d0 =
                    (unsigned long long)(q0 | (q1 << 16)) |
                    ((unsigned long long)(q2 | (q3 << 16)) << 32);
                const unsigned long long d1 =
                    (unsigned long long)(q4 | (q5 << 16)) |
                    ((unsigned long long)(q6 | (q7 << 16)) << 32);
                st_dev_u64(mdu + 2 * bid,     d0);
                st_dev_u64(mdu + 2 * bid + 1, d1);
                asm volatile("s_waitcnt vmcnt(0)" ::: "memory");
                st_dev_u32(mtu + bid, 2u * (unsigned)t + 1u);
            }
        }
        // wave 0: prefetch AFTER tag publish (keeps vmcnt(0) drain cheap)
        if (w == 0) {
            k0 = ld_nt_u4(MV + g0);       k1 = ld_nt_u4(MV + g0 + 64);
            k2 = ld_nt_u4(MV + g0 + 128); k3 = ld_nt_u4(MV + g0 + 192);
        }

        // ===== v-half operands: u(t), per-lane direct mailbox loads =====
        {
            const unsigned want = 2u * (unsigned)t + 1u;   // u(t) tag
            unsigned t0, t1, t2, t3;
            for (;;) {
                t0 = ld_dev_u32(mtu + e0); t1 = ld_dev_u32(mtu + e1);
                t2 = ld_dev_u32(mtu + e2); t3 = ld_dev_u32(mtu + e3);
                if (((t0 & 0x7fffffffu) == want) && ((t1 & 0x7fffffffu) == want) &&
                    ((t2 & 0x7fffffffu) == want) && ((t3 & 0x7fffffffu) == want))
                    break;
                __builtin_amdgcn_s_sleep(1);
            }
            asm volatile("" ::: "memory");
            va = ld_ent(mdu, e0); vb = ld_ent(mdu, e1);
            vc = ld_ent(mdu, e2); vd = ld_ent(mdu, e3);
        }

        // ===== v-half compute: v = b / (KTh . u) =====
        {
            float x0 = 0.f, x1 = 0.f, x2 = 0.f, x3 = 0.f;
            x0 = dot2(k0.x, va.x, x0); x0 = dot2(k0.y, va.y, x0);
            x0 = dot2(k0.z, va.z, x0); x0 = dot2(k0.w, va.w, x0);
            x1 = dot2(k1.x, vb.x, x1); x1 = dot2(k1.y, vb.y, x1);
            x1 = dot2(k1.z, vb.z, x1); x1 = dot2(k1.w, vb.w, x1);
            x2 = dot2(k2.x, vc.x, x2); x2 = dot2(k2.y, vc.y, x2);
            x2 = dot2(k2.z, vc.z, x2); x2 = dot2(k2.w, vc.w, x2);
            x3 = dot2(k3.x, vd.x, x3); x3 = dot2(k3.y, vd.y, x3);
            x3 = dot2(k3.z, vd.z, x3); x3 = dot2(k3.w, vd.w, x3);
            float acc = (x0 + x1) + (x2 + x3);
#pragma unroll
            for (int off = 32; off > 0; off >>= 1) acc += __shfl_down(acc, off, 64);
            if (lane == 0) part[w] = acc;
        }
        // waves 1..15: prefetch next u-half rows (plain cached)
        if (w != 0) {
            k0 = MU[g0]; k1 = MU[g0 + 64]; k2 = MU[g0 + 128]; k3 = MU[g0 + 192];
        }
        __syncthreads();
        if (w == 0) {   // publish v(t) (+freeze bit from register hist)
            unsigned hb = 0u;
            if (lane < 8) {
                float r = B_MARG / (part[2 * lane] + part[2 * lane + 1]);
                v32g[bid * 8 + lane] = r;
                hb = (unsigned)__half_as_ushort(__float2half(r));
            }
            const unsigned q0 = __shfl(hb, 0, 64), q1 = __shfl(hb, 1, 64);
            const unsigned q2 = __shfl(hb, 2, 64), q3 = __shfl(hb, 3, 64);
            const unsigned q4 = __shfl(hb, 4, 64), q5 = __shfl(hb, 5, 64);
            const unsigned q6 = __shfl(hb, 6, 64), q7 = __shfl(hb, 7, 64);
            if (lane == 0) {
                const unsigned long long d0 =
                    (unsigned long long)(q0 | (q1 << 16)) |
                    ((unsigned long long)(q2 | (q3 << 16)) << 32);
                const unsigned long long d1 =
                    (unsigned long long)(q4 | (q5 << 16)) |
                    ((unsigned long long)(q6 | (q7 << 16)) << 32);
                unsigned tg = 2u * (unsigned)t + 2u;
                if (t & 1) {   // v(t) vs v(t-2), register-resident history
                    if (d0 == h0p && d1 == h1p) tg |= 0x80000000u;
                    h0p = d0; h1p = d1;
                }
                st_dev_u64(mdv + 2 * bid,     d0);
                st_dev_u64(mdv + 2 * bid + 1, d1);
                asm volatile("s_waitcnt vmcnt(0)" ::: "memory");
                st_dev_u32(mtv + bid, tg);
            }
        }
        if (w == 0) {
            k0 = MU[g0]; k1 = MU[g0 + 64]; k2 = MU[g0 + 128]; k3 = MU[g0 + 192];
        }
    }
}

// ---------------------------------------------------------------------------
// Fallback per-iteration rowpasses (identical to R6; used only if the
// cooperative launch is rejected under graph capture).
// ---------------------------------------------------------------------------
__global__ void __launch_bounds__(1024, 8)
rowpass_u(const __half* __restrict__ Mat, const __half* __restrict__ w16_in,
          float* __restrict__ w32_out, __half* __restrict__ w16_out,
          unsigned* __restrict__ conv, unsigned* __restrict__ slot, int t) {
    if (ld_dev_u32(conv)) return;
    if ((t & 1) == 0) {
        if (ld_dev_u32(slot) == 0u) {
            if (threadIdx.x == 0) st_dev_u32(conv, 1u);
            return;
        }
    } else {
        if (blockIdx.x == 0 && threadIdx.x == 0) st_dev_u32(slot, 0u);
    }

    __shared__ __align__(16) __half vlds[MM];
    __shared__ float part[16];
    const int tid  = threadIdx.x;
    const int lane = tid & 63;
    const int w    = tid >> 6;
    const int rib  = w >> 1;
    const int hlf  = w & 1;
    const int i    = blockIdx.x * 8 + rib;
    const uint4* __restrict__ Mrow = (const uint4*)(Mat + (size_t)i * MM);
    const int g0 = hlf * 256 + lane;

    uint4 stg;
    if (tid < 512) stg = ((const uint4*)w16_in)[tid];
    const uint4 k0 = Mrow[g0];
    const uint4 k1 = Mrow[g0 + 64];
    const uint4 k2 = Mrow[g0 + 128];
    const uint4 k3 = Mrow[g0 + 192];
    if (tid < 512) ((uint4*)vlds)[tid] = stg;
    __syncthreads();

    const uint4* V = (const uint4*)vlds;
    const uint4 v0 = V[g0];
    const uint4 v1 = V[g0 + 64];
    const uint4 v2 = V[g0 + 128];
    const uint4 v3 = V[g0 + 192];

    float a0 = 0.f, a1 = 0.f, a2 = 0.f, a3 = 0.f;
    a0 = dot2(k0.x, v0.x, a0); a0 = dot2(k0.y, v0.y, a0);
    a0 = dot2(k0.z, v0.z, a0); a0 = dot2(k0.w, v0.w, a0);
    a1 = dot2(k1.x, v1.x, a1); a1 = dot2(k1.y, v1.y, a1);
    a1 = dot2(k1.z, v1.z, a1); a1 = dot2(k1.w, v1.w, a1);
    a2 = dot2(k2.x, v2.x, a2); a2 = dot2(k2.y, v2.y, a2);
    a2 = dot2(k2.z, v2.z, a2); a2 = dot2(k2.w, v2.w, a2);
    a3 = dot2(k3.x, v3.x, a3); a3 = dot2(k3.y, v3.y, a3);
    a3 = dot2(k3.z, v3.z, a3); a3 = dot2(k3.w, v3.w, a3);
    float acc = (a0 + a1) + (a2 + a3);

#pragma unroll
    for (int off = 32; off > 0; off >>= 1) acc += __shfl_down(acc, off, 64);
    if (lane == 0) part[w] = acc;
    __syncthreads();

    if (tid < 8) {
        const int row = blockIdx.x * 8 + tid;
        float r = A_MARG / (part[2 * tid] + part[2 * tid + 1]);
        w32_out[row] = r;
        w16_out[row] = __float2half(r);
    }
}

__global__ void __launch_bounds__(1024, 8)
rowpass_v(const __half* __restrict__ Mat, const __half* __restrict__ w16_in,
          float* __restrict__ w32_out, __half* __restrict__ w16_out,
          unsigned short* __restrict__ hist,
          unsigned* __restrict__ conv, unsigned* __restrict__ slot, int t) {
    if (ld_dev_u32(conv)) return;

    __shared__ __align__(16) __half vlds[MM];
    __shared__ float part[16];
    const int tid  = threadIdx.x;
    const int lane = tid & 63;
    const int w    = tid >> 6;
    const int rib  = w >> 1;
    const int hlf  = w & 1;
    const int i    = blockIdx.x * 8 + rib;
    const uint4* __restrict__ Mrow = (const uint4*)(Mat + (size_t)i * MM);
    const int g0 = hlf * 256 + lane;

    uint4 stg;
    if (tid < 512) stg = ((const uint4*)w16_in)[tid];
    const uint4 k0 = Mrow[g0];
    const uint4 k1 = Mrow[g0 + 64];
    const uint4 k2 = Mrow[g0 + 128];
    const uint4 k3 = Mrow[g0 + 192];
    if (tid < 512) ((uint4*)vlds)[tid] = stg;
    __syncthreads();

    const uint4* V = (const uint4*)vlds;
    const uint4 v0 = V[g0];
    const uint4 v1 = V[g0 + 64];
    const uint4 v2 = V[g0 + 128];
    const uint4 v3 = V[g0 + 192];

    float a0 = 0.f, a1 = 0.f, a2 = 0.f, a3 = 0.f;
    a0 = dot2(k0.x, v0.x, a0); a0 = dot2(k0.y, v0.y, a0);
    a0 = dot2(k0.z, v0.z, a0); a0 = dot2(k0.w, v0.w, a0);
    a1 = dot2(k1.x, v1.x, a1); a1 = dot2(k1.y, v1.y, a1);
    a1 = dot2(k1.z, v1.z, a1); a1 = dot2(k1.w, v1.w, a1);
    a2 = dot2(k2.x, v2.x, a2); a2 = dot2(k2.y, v2.y, a2);
    a2 = dot2(k2.z, v2.z, a2); a2 = dot2(k2.w, v2.w, a2);
    a3 = dot2(k3.x, v3.x, a3); a3 = dot2(k3.y, v3.y, a3);
    a3 = dot2(k3.z, v3.z, a3); a3 = dot2(k3.w, v3.w, a3);
    float acc = (a0 + a1) + (a2 + a3);

#pragma unroll
    for (int off = 32; off > 0; off >>= 1) acc += __shfl_down(acc, off, 64);
    if (lane == 0) part[w] = acc;
    __syncthreads();

    if (tid < 8) {
        const int row = blockIdx.x * 8 + tid;
        float r = B_MARG / (part[2 * tid] + part[2 * tid + 1]);
        w32_out[row] = r;
        const __half h = __float2half(r);
        if (t & 1) {
            const unsigned short bits = __half_as_ushort(h);
            const unsigned short old2 = ld_dev_u16(hist + row);
            if (old2 != bits) st_dev_u32(slot, 1u);
            st_dev_u16(hist + row, bits);
        }
        w16_out[row] = h;
    }
}

// ---------------------------------------------------------------------------
// gamma[i][j] = u[i] * exp(-||x_i-y_j||^2/reg) * v[j]   (exact fp32 K)
// grid: (16, 256), block 256
// ---------------------------------------------------------------------------
__global__ void epilogue(const float* __restrict__ x, const float* __restrict__ y,
                         const float* __restrict__ u, const float* __restrict__ v,
                         float* __restrict__ out) {
    const int tid = threadIdx.x;
    const int j   = blockIdx.x * 256 + tid;
    const int r0  = blockIdx.y * 16;

    float yv[DD];
    const float4* y4 = (const float4*)(y + (size_t)j * DD);
#pragma unroll
    for (int k = 0; k < DD / 4; ++k) {
        float4 t = y4[k];
        yv[4 * k + 0] = t.x; yv[4 * k + 1] = t.y;
        yv[4 * k + 2] = t.z; yv[4 * k + 3] = t.w;
    }

    __shared__ float xs[16 * DD];
    __shared__ float u_lds[16];
    xs[tid]       = x[(size_t)r0 * DD + tid];
    xs[tid + 256] = x[(size_t)r0 * DD + tid + 256];
    if (tid < 16) u_lds[tid] = u[r0 + tid];
    __syncthreads();

    const float vj = v[j];
#pragma unroll 4
    for (int ii = 0; ii < 16; ++ii) {
        float acc = 0.0f;
#pragma unroll
        for (int k = 0; k < DD; ++k) {
            float d = xs[ii * DD + k] - yv[k];
            acc = fmaf(d, d, acc);
        }
        out[(size_t)(r0 + ii) * MM + j] = u_lds[ii] * __expf(-acc * INV_REG) * vj;
    }
}

extern "C" void kernel_launch(void* const* d_in, const int* in_sizes, int n_in,
                              void* d_out, int out_size, void* d_ws, size_t ws_size,
                              hipStream_t stream) {
    const float* x = (const float*)d_in[0];
    const float* y = (const float*)d_in[1];
    __half*   Kh   = (__half*)d_ws;                    // 32 MB
    __half*   KTh  = Kh + (size_t)NN * MM;             // 32 MB
    float*    u32  = (float*)(KTh + (size_t)NN * MM);  // 16 KB
    float*    v32  = u32 + NN;                         // 16 KB
    __half*   u16  = (__half*)(v32 + MM);              // 8 KB (fallback)
    __half*   v16  = u16 + NN;                         // 8 KB (fallback)
    unsigned short* hist = (unsigned short*)(v16 + MM);// 8 KB (fallback; 0xAA-safe)
    unsigned* slot = (unsigned*)(hist + MM);           // 4 B (fallback)
    unsigned* conv = slot + 1;                         // 4 B (fallback)
    unsigned* mtu  = slot + 512;                       // 2 KB u-tags
    unsigned* mtv  = mtu + 512;                        // 2 KB v-tags
    unsigned long long* mdu = (unsigned long long*)(mtv + 512);  // 8 KB u-data
    unsigned long long* mdv = mdu + 1024;                        // 8 KB v-data
    float*    out  = (float*)d_out;

    compute_K_half<<<dim3(MM / 256, NN / 16), 256, 0, stream>>>(x, y, Kh, v16, conv, slot, mtu, mtv, 1);
    compute_K_half<<<dim3(NN / 256, MM / 16), 256, 0, stream>>>(y, x, KTh, v16, conv, slot, mtu, mtv, 0);

    {
        void* args[] = { &Kh, &KTh, &u32, &v32, &mtu, &mtv, &mdu, &mdv };
        hipError_t e = hipLaunchCooperativeKernel((const void*)sinkhorn_persist,
                                                  dim3(512), dim3(1024), args, 0, stream);
        if (e != hipSuccess) {
            (void)hipGetLastError();   // clear; fall back to per-iteration dispatches
            for (int t = 0; t < N_ITERS; ++t) {
                rowpass_u<<<NN / 8, 1024, 0, stream>>>(Kh,  v16, u32, u16, conv, slot, t);
                rowpass_v<<<MM / 8, 1024, 0, stream>>>(KTh, u16, v32, v16, hist, conv, slot, t);
            }
        }
    }

    epilogue<<<dim3(MM / 256, NN / 16), 256, 0, stream>>>(x, y, u32, v32, out);
}

// Round 8
// 614.540 us; speedup vs baseline: 1.6539x; 1.6539x over previous
//
#include <hip/hip_runtime.h>
#include <hip/hip_fp16.h>

// Sinkhorn OT: n=m=4096, d=32, reg=0.1, 100 iterations, uniform marginals.
// R13 = R11 (mailbox persistent kernel WITH LDS staging) + MATRIX IN
// REGISTERS. R12 post-mortem: per-lane direct mailbox operand loads were 8x
// redundant coherent traffic (FETCH +50%, 838us) -> LDS staging restored.
// New: the chip has 128 MB of VGPR (256 CU x 512 KB); K+K^T is 64 MB. Each
// lane's matrix share in this partition is exactly 8 uint4 = 32 VGPR, so
// BOTH halves are loaded ONCE before the loop and stay register-resident:
// the loop has ZERO matrix memory traffic (was 32 MB/half-pass). LDS-staged
// mailbox operands (8 KB/block), dot from registers, publish. launch_bounds
// (1024,8) caps VGPR at 64 -> full 2-blocks/CU co-residency preserved.
// Kept from R12 (not implicated in its regression): parallel publish (lanes
// 0-7 divide, shfl-pack, lane0 data->vmcnt(0)->tag) and register-resident
// freeze history. Freeze bit rides in v-tag bit31; uniform break at even t.
// Numerics bit-identical to R11 (same operand values, same accumulation
// order; only the K operand residency changed).
// Fallback: R6 per-iteration dispatch loop if cooperative launch fails.

#define NN 4096
#define MM 4096
#define DD 32
#define N_ITERS 100

static constexpr float INV_REG = 10.0f;
static constexpr float A_MARG  = 1.0f / 4096.0f;
static constexpr float B_MARG  = 1.0f / 4096.0f;

typedef _Float16 h2_t __attribute__((ext_vector_type(2)));

static __device__ __forceinline__ float dot2(unsigned a, unsigned b, float acc) {
#if __has_builtin(__builtin_amdgcn_fdot2)
    return __builtin_amdgcn_fdot2(__builtin_bit_cast(h2_t, a),
                                  __builtin_bit_cast(h2_t, b), acc, false);
#else
    float2 fa = __half22float2(*(const __half2*)&a);
    float2 fb = __half22float2(*(const __half2*)&b);
    acc = fmaf(fa.x, fb.x, acc);
    return fmaf(fa.y, fb.y, acc);
#endif
}

static __device__ __forceinline__ unsigned ld_dev_u32(const unsigned* p) {
    return __hip_atomic_load(p, __ATOMIC_RELAXED, __HIP_MEMORY_SCOPE_AGENT);
}
static __device__ __forceinline__ void st_dev_u32(unsigned* p, unsigned v) {
    __hip_atomic_store(p, v, __ATOMIC_RELAXED, __HIP_MEMORY_SCOPE_AGENT);
}
static __device__ __forceinline__ unsigned short ld_dev_u16(const unsigned short* p) {
    return __hip_atomic_load(p, __ATOMIC_RELAXED, __HIP_MEMORY_SCOPE_AGENT);
}
static __device__ __forceinline__ void st_dev_u16(unsigned short* p, unsigned short v) {
    __hip_atomic_store(p, v, __ATOMIC_RELAXED, __HIP_MEMORY_SCOPE_AGENT);
}
static __device__ __forceinline__ unsigned long long ld_dev_u64(const unsigned long long* p) {
    return __hip_atomic_load(p, __ATOMIC_RELAXED, __HIP_MEMORY_SCOPE_AGENT);
}
static __device__ __forceinline__ void st_dev_u64(unsigned long long* p, unsigned long long v) {
    __hip_atomic_store(p, v, __ATOMIC_RELAXED, __HIP_MEMORY_SCOPE_AGENT);
}

// ---------------------------------------------------------------------------
// Kh[i][j] = (half)exp(-||p_i - q_j||^2 / reg). prime!=0: v16=1/4096,
// conv=0, slot=1 (fallback path), mailbox tags zeroed.
// grid: (4096/256, 4096/16), block 256
// ---------------------------------------------------------------------------
__global__ void compute_K_half(const float* __restrict__ p, const float* __restrict__ q,
                               __half* __restrict__ Kh, __half* __restrict__ v16,
                               unsigned* __restrict__ conv, unsigned* __restrict__ slot,
                               unsigned* __restrict__ mtu, unsigned* __restrict__ mtv,
                               int prime) {
    const int tid = threadIdx.x;
    const int j   = blockIdx.x * 256 + tid;
    const int r0  = blockIdx.y * 16;

    if (prime && blockIdx.y == 0) {
        v16[j] = __float2half(B_MARG);
        if (blockIdx.x == 0) {
            if (tid == 0) { *conv = 0u; *slot = 1u; }
            mtu[tid] = 0u; mtu[tid + 256] = 0u;
            mtv[tid] = 0u; mtv[tid + 256] = 0u;
        }
    }

    float qv[DD];
    const float4* q4 = (const float4*)(q + (size_t)j * DD);
#pragma unroll
    for (int k = 0; k < DD / 4; ++k) {
        float4 t = q4[k];
        qv[4 * k + 0] = t.x; qv[4 * k + 1] = t.y;
        qv[4 * k + 2] = t.z; qv[4 * k + 3] = t.w;
    }

    __shared__ float ps[16 * DD];
    ps[tid]       = p[(size_t)r0 * DD + tid];
    ps[tid + 256] = p[(size_t)r0 * DD + tid + 256];
    __syncthreads();

#pragma unroll 4
    for (int ii = 0; ii < 16; ++ii) {
        float acc = 0.0f;
#pragma unroll
        for (int k = 0; k < DD; ++k) {
            float d = ps[ii * DD + k] - qv[k];
            acc = fmaf(d, d, acc);
        }
        Kh[(size_t)(r0 + ii) * MM + j] = __float2half(__expf(-acc * INV_REG));
    }
}

// ---------------------------------------------------------------------------
// Persistent kernel: all 100 iterations, mailbox-synced, matrix in VGPRs.
// 512 blocks x 1024 thr (16 waves), 2 waves per row, 4 fdot2 chains.
// Bit-identical accumulation order to R11.
// ---------------------------------------------------------------------------
__global__ void __launch_bounds__(1024, 8)
sinkhorn_persist(const __half* __restrict__ Kh, const __half* __restrict__ KTh,
                 float* __restrict__ u32g, float* __restrict__ v32g,
                 unsigned* __restrict__ mtu, unsigned* __restrict__ mtv,
                 unsigned long long* __restrict__ mdu,
                 unsigned long long* __restrict__ mdv) {
    __shared__ __align__(16) __half vlds[MM];
    __shared__ float part[16];
    __shared__ unsigned fb_lds[8];
    const int tid  = threadIdx.x;
    const int lane = tid & 63;
    const int w    = tid >> 6;          // wave 0..15
    const int rib  = w >> 1;            // row-in-block 0..7
    const int hlf  = w & 1;             // half-row
    const int bid  = blockIdx.x;
    const int i    = bid * 8 + rib;
    const int g0   = hlf * 256 + lane;  // uint4 index into 512-uint4 row
    const uint4* __restrict__ MU = (const uint4*)(Kh  + (size_t)i * MM);
    const uint4* __restrict__ MV = (const uint4*)(KTh + (size_t)i * MM);

    // ---- matrix rows -> registers, ONCE (8 uint4 = 32 VGPR/lane) ----
    const uint4 ku0 = MU[g0], ku1 = MU[g0 + 64], ku2 = MU[g0 + 128], ku3 = MU[g0 + 192];
    const uint4 kv0 = MV[g0], kv1 = MV[g0 + 64], kv2 = MV[g0 + 128], kv3 = MV[g0 + 192];

    // freeze history: block-private 16B in lane0-of-wave0 registers.
    unsigned long long h0p = ~0ULL, h1p = ~0ULL;

    for (int t = 0; t < N_ITERS; ++t) {
        // ===== u-half stage: v(t-1) -> LDS (one coherent load per entry) =====
        if (t == 0) {
            if (tid < 512) {
                const unsigned long long dv =
                    (unsigned long long)__half_as_ushort(__float2half(B_MARG)) *
                    0x0001000100010001ULL;
                ((unsigned long long*)vlds)[2 * tid]     = dv;
                ((unsigned long long*)vlds)[2 * tid + 1] = dv;
            }
            __syncthreads();
        } else {
            if (tid < 512) {
                const unsigned want = 2u * (unsigned)t;   // v(t-1) tag
                unsigned tg;
                for (;;) {
                    tg = ld_dev_u32(mtv + tid);
                    if ((tg & 0x7fffffffu) == want) break;
                    __builtin_amdgcn_s_sleep(1);
                }
                asm volatile("" ::: "memory");   // no hoist of data loads above poll
                unsigned long long d0 = ld_dev_u64(mdv + 2 * tid);
                unsigned long long d1 = ld_dev_u64(mdv + 2 * tid + 1);
                ((unsigned long long*)vlds)[2 * tid]     = d0;
                ((unsigned long long*)vlds)[2 * tid + 1] = d1;
                const bool allf = __all((tg >> 31) != 0u);
                if ((tid & 63) == 0) fb_lds[tid >> 6] = allf ? 1u : 0u;
            }
            __syncthreads();
            if ((t & 1) == 0) {
                // v(t-1)==v(t-3) bitwise everywhere -> remaining iterations
                // bit-identical; u32g/v32g already final. Exact skip.
                if ((fb_lds[0] & fb_lds[1] & fb_lds[2] & fb_lds[3] &
                     fb_lds[4] & fb_lds[5] & fb_lds[6] & fb_lds[7]) != 0u)
                    break;
            }
        }

        // ===== u-half compute: u = a / (Kh . v), matrix from registers =====
        {
            const uint4* V = (const uint4*)vlds;
            const uint4 a = V[g0], b = V[g0 + 64], c = V[g0 + 128], d = V[g0 + 192];
            float x0 = 0.f, x1 = 0.f, x2 = 0.f, x3 = 0.f;
            x0 = dot2(ku0.x, a.x, x0); x0 = dot2(ku0.y, a.y, x0);
            x0 = dot2(ku0.z, a.z, x0); x0 = dot2(ku0.w, a.w, x0);
            x1 = dot2(ku1.x, b.x, x1); x1 = dot2(ku1.y, b.y, x1);
            x1 = dot2(ku1.z, b.z, x1); x1 = dot2(ku1.w, b.w, x1);
            x2 = dot2(ku2.x, c.x, x2); x2 = dot2(ku2.y, c.y, x2);
            x2 = dot2(ku2.z, c.z, x2); x2 = dot2(ku2.w, c.w, x2);
            x3 = dot2(ku3.x, d.x, x3); x3 = dot2(ku3.y, d.y, x3);
            x3 = dot2(ku3.z, d.z, x3); x3 = dot2(ku3.w, d.w, x3);
            float acc = (x0 + x1) + (x2 + x3);
#pragma unroll
            for (int off = 32; off > 0; off >>= 1) acc += __shfl_down(acc, off, 64);
            if (lane == 0) part[w] = acc;
        }
        __syncthreads();
        if (w == 0) {   // publish u(t): parallel divides, shfl pack, lane0 tag
            unsigned hb = 0u;
            if (lane < 8) {
                float r = A_MARG / (part[2 * lane] + part[2 * lane + 1]);
                u32g[bid * 8 + lane] = r;
                hb = (unsigned)__half_as_ushort(__float2half(r));
            }
            const unsigned q0 = __shfl(hb, 0, 64), q1 = __shfl(hb, 1, 64);
            const unsigned q2 = __shfl(hb, 2, 64), q3 = __shfl(hb, 3, 64);
            const unsigned q4 = __shfl(hb, 4, 64), q5 = __shfl(hb, 5, 64);
            const unsigned q6 = __shfl(hb, 6, 64), q7 = __shfl(hb, 7, 64);
            if (lane == 0) {
                const unsigned long long d0 =
                    (unsigned long long)(q0 | (q1 << 16)) |
                    ((unsigned long long)(q2 | (q3 << 16)) << 32);
                const unsigned long long d1 =
                    (unsigned long long)(q4 | (q5 << 16)) |
                    ((unsigned long long)(q6 | (q7 << 16)) << 32);
                st_dev_u64(mdu + 2 * bid,     d0);
                st_dev_u64(mdu + 2 * bid + 1, d1);
                asm volatile("s_waitcnt vmcnt(0)" ::: "memory");
                st_dev_u32(mtu + bid, 2u * (unsigned)t + 1u);
            }
        }

        // ===== v-half stage: u(t) -> LDS =====
        if (tid < 512) {
            const unsigned want = 2u * (unsigned)t + 1u;   // u(t) tag
            unsigned tg;
            for (;;) {
                tg = ld_dev_u32(mtu + tid);
                if ((tg & 0x7fffffffu) == want) break;
                __builtin_amdgcn_s_sleep(1);
            }
            asm volatile("" ::: "memory");
            unsigned long long d0 = ld_dev_u64(mdu + 2 * tid);
            unsigned long long d1 = ld_dev_u64(mdu + 2 * tid + 1);
            ((unsigned long long*)vlds)[2 * tid]     = d0;
            ((unsigned long long*)vlds)[2 * tid + 1] = d1;
        }
        __syncthreads();

        // ===== v-half compute: v = b / (KTh . u), matrix from registers =====
        {
            const uint4* V = (const uint4*)vlds;
            const uint4 a = V[g0], b = V[g0 + 64], c = V[g0 + 128], d = V[g0 + 192];
            float x0 = 0.f, x1 = 0.f, x2 = 0.f, x3 = 0.f;
            x0 = dot2(kv0.x, a.x, x0); x0 = dot2(kv0.y, a.y, x0);
            x0 = dot2(kv0.z, a.z, x0); x0 = dot2(kv0.w, a.w, x0);
            x1 = dot2(kv1.x, b.x, x1); x1 = dot2(kv1.y, b.y, x1);
            x1 = dot2(kv1.z, b.z, x1); x1 = dot2(kv1.w, b.w, x1);
            x2 = dot2(kv2.x, c.x, x2); x2 = dot2(kv2.y, c.y, x2);
            x2 = dot2(kv2.z, c.z, x2); x2 = dot2(kv2.w, c.w, x2);
            x3 = dot2(kv3.x, d.x, x3); x3 = dot2(kv3.y, d.y, x3);
            x3 = dot2(kv3.z, d.z, x3); x3 = dot2(kv3.w, d.w, x3);
            float acc = (x0 + x1) + (x2 + x3);
#pragma unroll
            for (int off = 32; off > 0; off >>= 1) acc += __shfl_down(acc, off, 64);
            if (lane == 0) part[w] = acc;
        }
        __syncthreads();
        if (w == 0) {   // publish v(t) (+freeze bit from register hist)
            unsigned hb = 0u;
            if (lane < 8) {
                float r = B_MARG / (part[2 * lane] + part[2 * lane + 1]);
                v32g[bid * 8 + lane] = r;
                hb = (unsigned)__half_as_ushort(__float2half(r));
            }
            const unsigned q0 = __shfl(hb, 0, 64), q1 = __shfl(hb, 1, 64);
            const unsigned q2 = __shfl(hb, 2, 64), q3 = __shfl(hb, 3, 64);
            const unsigned q4 = __shfl(hb, 4, 64), q5 = __shfl(hb, 5, 64);
            const unsigned q6 = __shfl(hb, 6, 64), q7 = __shfl(hb, 7, 64);
            if (lane == 0) {
                const unsigned long long d0 =
                    (unsigned long long)(q0 | (q1 << 16)) |
                    ((unsigned long long)(q2 | (q3 << 16)) << 32);
                const unsigned long long d1 =
                    (unsigned long long)(q4 | (q5 << 16)) |
                    ((unsigned long long)(q6 | (q7 << 16)) << 32);
                unsigned tg = 2u * (unsigned)t + 2u;
                if (t & 1) {   // v(t) vs v(t-2), register-resident history
                    if (d0 == h0p && d1 == h1p) tg |= 0x80000000u;
                    h0p = d0; h1p = d1;
                }
                st_dev_u64(mdv + 2 * bid,     d0);
                st_dev_u64(mdv + 2 * bid + 1, d1);
                asm volatile("s_waitcnt vmcnt(0)" ::: "memory");
                st_dev_u32(mtv + bid, tg);
            }
        }
    }
}

// ---------------------------------------------------------------------------
// Fallback per-iteration rowpasses (identical to R6; used only if the
// cooperative launch is rejected under graph capture).
// ---------------------------------------------------------------------------
__global__ void __launch_bounds__(1024, 8)
rowpass_u(const __half* __restrict__ Mat, const __half* __restrict__ w16_in,
          float* __restrict__ w32_out, __half* __restrict__ w16_out,
          unsigned* __restrict__ conv, unsigned* __restrict__ slot, int t) {
    if (ld_dev_u32(conv)) return;
    if ((t & 1) == 0) {
        if (ld_dev_u32(slot) == 0u) {
            if (threadIdx.x == 0) st_dev_u32(conv, 1u);
            return;
        }
    } else {
        if (blockIdx.x == 0 && threadIdx.x == 0) st_dev_u32(slot, 0u);
    }

    __shared__ __align__(16) __half vlds[MM];
    __shared__ float part[16];
    const int tid  = threadIdx.x;
    const int lane = tid & 63;
    const int w    = tid >> 6;
    const int rib  = w >> 1;
    const int hlf  = w & 1;
    const int i    = blockIdx.x * 8 + rib;
    const uint4* __restrict__ Mrow = (const uint4*)(Mat + (size_t)i * MM);
    const int g0 = hlf * 256 + lane;

    uint4 stg;
    if (tid < 512) stg = ((const uint4*)w16_in)[tid];
    const uint4 k0 = Mrow[g0];
    const uint4 k1 = Mrow[g0 + 64];
    const uint4 k2 = Mrow[g0 + 128];
    const uint4 k3 = Mrow[g0 + 192];
    if (tid < 512) ((uint4*)vlds)[tid] = stg;
    __syncthreads();

    const uint4* V = (const uint4*)vlds;
    const uint4 v0 = V[g0];
    const uint4 v1 = V[g0 + 64];
    const uint4 v2 = V[g0 + 128];
    const uint4 v3 = V[g0 + 192];

    float a0 = 0.f, a1 = 0.f, a2 = 0.f, a3 = 0.f;
    a0 = dot2(k0.x, v0.x, a0); a0 = dot2(k0.y, v0.y, a0);
    a0 = dot2(k0.z, v0.z, a0); a0 = dot2(k0.w, v0.w, a0);
    a1 = dot2(k1.x, v1.x, a1); a1 = dot2(k1.y, v1.y, a1);
    a1 = dot2(k1.z, v1.z, a1); a1 = dot2(k1.w, v1.w, a1);
    a2 = dot2(k2.x, v2.x, a2); a2 = dot2(k2.y, v2.y, a2);
    a2 = dot2(k2.z, v2.z, a2); a2 = dot2(k2.w, v2.w, a2);
    a3 = dot2(k3.x, v3.x, a3); a3 = dot2(k3.y, v3.y, a3);
    a3 = dot2(k3.z, v3.z, a3); a3 = dot2(k3.w, v3.w, a3);
    float acc = (a0 + a1) + (a2 + a3);

#pragma unroll
    for (int off = 32; off > 0; off >>= 1) acc += __shfl_down(acc, off, 64);
    if (lane == 0) part[w] = acc;
    __syncthreads();

    if (tid < 8) {
        const int row = blockIdx.x * 8 + tid;
        float r = A_MARG / (part[2 * tid] + part[2 * tid + 1]);
        w32_out[row] = r;
        w16_out[row] = __float2half(r);
    }
}

__global__ void __launch_bounds__(1024, 8)
rowpass_v(const __half* __restrict__ Mat, const __half* __restrict__ w16_in,
          float* __restrict__ w32_out, __half* __restrict__ w16_out,
          unsigned short* __restrict__ hist,
          unsigned* __restrict__ conv, unsigned* __restrict__ slot, int t) {
    if (ld_dev_u32(conv)) return;

    __shared__ __align__(16) __half vlds[MM];
    __shared__ float part[16];
    const int tid  = threadIdx.x;
    const int lane = tid & 63;
    const int w    = tid >> 6;
    const int rib  = w >> 1;
    const int hlf  = w & 1;
    const int i    = blockIdx.x * 8 + rib;
    const uint4* __restrict__ Mrow = (const uint4*)(Mat + (size_t)i * MM);
    const int g0 = hlf * 256 + lane;

    uint4 stg;
    if (tid < 512) stg = ((const uint4*)w16_in)[tid];
    const uint4 k0 = Mrow[g0];
    const uint4 k1 = Mrow[g0 + 64];
    const uint4 k2 = Mrow[g0 + 128];
    const uint4 k3 = Mrow[g0 + 192];
    if (tid < 512) ((uint4*)vlds)[tid] = stg;
    __syncthreads();

    const uint4* V = (const uint4*)vlds;
    const uint4 v0 = V[g0];
    const uint4 v1 = V[g0 + 64];
    const uint4 v2 = V[g0 + 128];
    const uint4 v3 = V[g0 + 192];

    float a0 = 0.f, a1 = 0.f, a2 = 0.f, a3 = 0.f;
    a0 = dot2(k0.x, v0.x, a0); a0 = dot2(k0.y, v0.y, a0);
    a0 = dot2(k0.z, v0.z, a0); a0 = dot2(k0.w, v0.w, a0);
    a1 = dot2(k1.x, v1.x, a1); a1 = dot2(k1.y, v1.y, a1);
    a1 = dot2(k1.z, v1.z, a1); a1 = dot2(k1.w, v1.w, a1);
    a2 = dot2(k2.x, v2.x, a2); a2 = dot2(k2.y, v2.y, a2);
    a2 = dot2(k2.z, v2.z, a2); a2 = dot2(k2.w, v2.w, a2);
    a3 = dot2(k3.x, v3.x, a3); a3 = dot2(k3.y, v3.y, a3);
    a3 = dot2(k3.z, v3.z, a3); a3 = dot2(k3.w, v3.w, a3);
    float acc = (a0 + a1) + (a2 + a3);

#pragma unroll
    for (int off = 32; off > 0; off >>= 1) acc += __shfl_down(acc, off, 64);
    if (lane == 0) part[w] = acc;
    __syncthreads();

    if (tid < 8) {
        const int row = blockIdx.x * 8 + tid;
        float r = B_MARG / (part[2 * tid] + part[2 * tid + 1]);
        w32_out[row] = r;
        const __half h = __float2half(r);
        if (t & 1) {
            const unsigned short bits = __half_as_ushort(h);
            const unsigned short old2 = ld_dev_u16(hist + row);
            if (old2 != bits) st_dev_u32(slot, 1u);
            st_dev_u16(hist + row, bits);
        }
        w16_out[row] = h;
    }
}

// ---------------------------------------------------------------------------
// gamma[i][j] = u[i] * exp(-||x_i-y_j||^2/reg) * v[j]   (exact fp32 K)
// grid: (16, 256), block 256
// ---------------------------------------------------------------------------
__global__ void epilogue(const float* __restrict__ x, const float* __restrict__ y,
                         const float* __restrict__ u, const float* __restrict__ v,
                         float* __restrict__ out) {
    const int tid = threadIdx.x;
    const int j   = blockIdx.x * 256 + tid;
    const int r0  = blockIdx.y * 16;

    float yv[DD];
    const float4* y4 = (const float4*)(y + (size_t)j * DD);
#pragma unroll
    for (int k = 0; k < DD / 4; ++k) {
        float4 t = y4[k];
        yv[4 * k + 0] = t.x; yv[4 * k + 1] = t.y;
        yv[4 * k + 2] = t.z; yv[4 * k + 3] = t.w;
    }

    __shared__ float xs[16 * DD];
    __shared__ float u_lds[16];
    xs[tid]       = x[(size_t)r0 * DD + tid];
    xs[tid + 256] = x[(size_t)r0 * DD + tid + 256];
    if (tid < 16) u_lds[tid] = u[r0 + tid];
    __syncthreads();

    const float vj = v[j];
#pragma unroll 4
    for (int ii = 0; ii < 16; ++ii) {
        float acc = 0.0f;
#pragma unroll
        for (int k = 0; k < DD; ++k) {
            float d = xs[ii * DD + k] - yv[k];
            acc = fmaf(d, d, acc);
        }
        out[(size_t)(r0 + ii) * MM + j] = u_lds[ii] * __expf(-acc * INV_REG) * vj;
    }
}

extern "C" void kernel_launch(void* const* d_in, const int* in_sizes, int n_in,
                              void* d_out, int out_size, void* d_ws, size_t ws_size,
                              hipStream_t stream) {
    const float* x = (const float*)d_in[0];
    const float* y = (const float*)d_in[1];
    __half*   Kh   = (__half*)d_ws;                    // 32 MB
    __half*   KTh  = Kh + (size_t)NN * MM;             // 32 MB
    float*    u32  = (float*)(KTh + (size_t)NN * MM);  // 16 KB
    float*    v32  = u32 + NN;                         // 16 KB
    __half*   u16  = (__half*)(v32 + MM);              // 8 KB (fallback)
    __half*   v16  = u16 + NN;                         // 8 KB (fallback)
    unsigned short* hist = (unsigned short*)(v16 + MM);// 8 KB (fallback; 0xAA-safe)
    unsigned* slot = (unsigned*)(hist + MM);           // 4 B (fallback)
    unsigned* conv = slot + 1;                         // 4 B (fallback)
    unsigned* mtu  = slot + 512;                       // 2 KB u-tags
    unsigned* mtv  = mtu + 512;                        // 2 KB v-tags
    unsigned long long* mdu = (unsigned long long*)(mtv + 512);  // 8 KB u-data
    unsigned long long* mdv = mdu + 1024;                        // 8 KB v-data
    float*    out  = (float*)d_out;

    compute_K_half<<<dim3(MM / 256, NN / 16), 256, 0, stream>>>(x, y, Kh, v16, conv, slot, mtu, mtv, 1);
    compute_K_half<<<dim3(NN / 256, MM / 16), 256, 0, stream>>>(y, x, KTh, v16, conv, slot, mtu, mtv, 0);

    {
        void* args[] = { &Kh, &KTh, &u32, &v32, &mtu, &mtv, &mdu, &mdv };
        hipError_t e = hipLaunchCooperativeKernel((const void*)sinkhorn_persist,
                                                  dim3(512), dim3(1024), args, 0, stream);
        if (e != hipSuccess) {
            (void)hipGetLastError();   // clear; fall back to per-iteration dispatches
            for (int t = 0; t < N_ITERS; ++t) {
                rowpass_u<<<NN / 8, 1024, 0, stream>>>(Kh,  v16, u32, u16, conv, slot, t);
                rowpass_v<<<MM / 8, 1024, 0, stream>>>(KTh, u16, v32, v16, hist, conv, slot, t);
            }
        }
    }

    epilogue<<<dim3(MM / 256, NN / 16), 256, 0, stream>>>(x, y, u32, v32, out);
}

// Round 9
// 576.677 us; speedup vs baseline: 1.7625x; 1.0657x over previous
//
#include <hip/hip_runtime.h>
#include <hip/hip_fp16.h>

// Sinkhorn OT: n=m=4096, d=32, reg=0.1, 100 iterations, uniform marginals.
// R14 = R13 (persistent kernel, matrix in VGPRs: FETCH 459->46MB proved the
// loop has zero matrix traffic) with the mailbox protocol FUSED:
// R13 post-mortem: runtime is 100% exchange-bound (~2.18us/half-pass); the
// critical path had TWO serialized fabric RTs (tag poll, then data load)
// plus a writer-side vmcnt(0) drain. New protocol: each row publishes ONE
// self-validating u32 = (val16<<16)|phase16. Reader that sees the right
// phase already holds the datum:
//   - one RT instead of two; no vmcnt drain; no lane0 shfl-pack funnel
//     (threads tid<8 store their row directly after the part[] combine)
//   - staging: thread tid poll-loads rows {k*512+tid} (lane-coalesced 4B),
//     strips phase, writes fp16 into vlds[row]
//   - freeze rides in phase bit15 (publishers tid<8 keep prev-prev val16 in
//     a register); readers AND bit15 over their 8 entries -> __all -> LDS
//     vote -> uniform exact break at even t. Phases monotone (2t+1 u, 2t+2
//     v, <0x7fff); depth-2 transitive chain makes slot reuse safe; 0xAA
//     poison phase (0x2AAA) never matches (and mailboxes are zeroed anyway).
// Numerics bit-identical to R11/R13 (same operand values, same order).
// Fallback: R6 per-iteration dispatch loop if cooperative launch fails.

#define NN 4096
#define MM 4096
#define DD 32
#define N_ITERS 100

static constexpr float INV_REG = 10.0f;
static constexpr float A_MARG  = 1.0f / 4096.0f;
static constexpr float B_MARG  = 1.0f / 4096.0f;

typedef _Float16 h2_t __attribute__((ext_vector_type(2)));

static __device__ __forceinline__ float dot2(unsigned a, unsigned b, float acc) {
#if __has_builtin(__builtin_amdgcn_fdot2)
    return __builtin_amdgcn_fdot2(__builtin_bit_cast(h2_t, a),
                                  __builtin_bit_cast(h2_t, b), acc, false);
#else
    float2 fa = __half22float2(*(const __half2*)&a);
    float2 fb = __half22float2(*(const __half2*)&b);
    acc = fmaf(fa.x, fb.x, acc);
    return fmaf(fa.y, fb.y, acc);
#endif
}

static __device__ __forceinline__ unsigned ld_dev_u32(const unsigned* p) {
    return __hip_atomic_load(p, __ATOMIC_RELAXED, __HIP_MEMORY_SCOPE_AGENT);
}
static __device__ __forceinline__ void st_dev_u32(unsigned* p, unsigned v) {
    __hip_atomic_store(p, v, __ATOMIC_RELAXED, __HIP_MEMORY_SCOPE_AGENT);
}
static __device__ __forceinline__ unsigned short ld_dev_u16(const unsigned short* p) {
    return __hip_atomic_load(p, __ATOMIC_RELAXED, __HIP_MEMORY_SCOPE_AGENT);
}
static __device__ __forceinline__ void st_dev_u16(unsigned short* p, unsigned short v) {
    __hip_atomic_store(p, v, __ATOMIC_RELAXED, __HIP_MEMORY_SCOPE_AGENT);
}

// ---------------------------------------------------------------------------
// Kh[i][j] = (half)exp(-||p_i - q_j||^2 / reg). prime!=0: v16=1/4096,
// conv=0, slot=1 (fallback path), row-mailboxes zeroed (phase 0 = invalid).
// grid: (4096/256, 4096/16), block 256
// ---------------------------------------------------------------------------
__global__ void compute_K_half(const float* __restrict__ p, const float* __restrict__ q,
                               __half* __restrict__ Kh, __half* __restrict__ v16,
                               unsigned* __restrict__ conv, unsigned* __restrict__ slot,
                               unsigned* __restrict__ mbu, unsigned* __restrict__ mbv,
                               int prime) {
    const int tid = threadIdx.x;
    const int j   = blockIdx.x * 256 + tid;
    const int r0  = blockIdx.y * 16;

    if (prime && blockIdx.y == 0) {
        v16[j] = __float2half(B_MARG);
        mbu[j] = 0u;
        mbv[j] = 0u;
        if (blockIdx.x == 0 && tid == 0) { *conv = 0u; *slot = 1u; }
    }

    float qv[DD];
    const float4* q4 = (const float4*)(q + (size_t)j * DD);
#pragma unroll
    for (int k = 0; k < DD / 4; ++k) {
        float4 t = q4[k];
        qv[4 * k + 0] = t.x; qv[4 * k + 1] = t.y;
        qv[4 * k + 2] = t.z; qv[4 * k + 3] = t.w;
    }

    __shared__ float ps[16 * DD];
    ps[tid]       = p[(size_t)r0 * DD + tid];
    ps[tid + 256] = p[(size_t)r0 * DD + tid + 256];
    __syncthreads();

#pragma unroll 4
    for (int ii = 0; ii < 16; ++ii) {
        float acc = 0.0f;
#pragma unroll
        for (int k = 0; k < DD; ++k) {
            float d = ps[ii * DD + k] - qv[k];
            acc = fmaf(d, d, acc);
        }
        Kh[(size_t)(r0 + ii) * MM + j] = __float2half(__expf(-acc * INV_REG));
    }
}

// ---------------------------------------------------------------------------
// Persistent kernel: all 100 iterations, fused val|phase row-mailboxes,
// matrix in VGPRs. 512 blocks x 1024 thr (16 waves), 2 waves per row,
// 4 fdot2 chains. Bit-identical accumulation order to R11/R13.
// ---------------------------------------------------------------------------
__global__ void __launch_bounds__(1024, 8)
sinkhorn_persist(const __half* __restrict__ Kh, const __half* __restrict__ KTh,
                 float* __restrict__ u32g, float* __restrict__ v32g,
                 unsigned* __restrict__ mbu, unsigned* __restrict__ mbv) {
    __shared__ __align__(16) __half vlds[MM];
    __shared__ float part[16];
    __shared__ unsigned fb_lds[8];
    const int tid  = threadIdx.x;
    const int lane = tid & 63;
    const int w    = tid >> 6;          // wave 0..15
    const int rib  = w >> 1;            // row-in-block 0..7
    const int hlf  = w & 1;             // half-row
    const int bid  = blockIdx.x;
    const int i    = bid * 8 + rib;
    const int g0   = hlf * 256 + lane;  // uint4 index into 512-uint4 row
    const uint4* __restrict__ MU = (const uint4*)(Kh  + (size_t)i * MM);
    const uint4* __restrict__ MV = (const uint4*)(KTh + (size_t)i * MM);
    unsigned short* __restrict__ vlh = (unsigned short*)vlds;

    // ---- matrix rows -> registers, ONCE (8 uint4 = 32 VGPR/lane) ----
    const uint4 ku0 = MU[g0], ku1 = MU[g0 + 64], ku2 = MU[g0 + 128], ku3 = MU[g0 + 192];
    const uint4 kv0 = MV[g0], kv1 = MV[g0 + 64], kv2 = MV[g0 + 128], kv3 = MV[g0 + 192];

    // freeze history: per-row prev-prev val16, register of thread tid<8.
    unsigned histv = 0x10000u;   // impossible 16-bit value

    for (int t = 0; t < N_ITERS; ++t) {
        // ===== u-half stage: v(t-1) rows {k*512+tid} -> LDS =====
        if (t == 0) {
            if (tid < 512) {
                const unsigned long long dv =
                    (unsigned long long)__half_as_ushort(__float2half(B_MARG)) *
                    0x0001000100010001ULL;
                ((unsigned long long*)vlds)[2 * tid]     = dv;
                ((unsigned long long*)vlds)[2 * tid + 1] = dv;
            }
            __syncthreads();
        } else {
            if (tid < 512) {
                const unsigned want = (unsigned)(2 * t) & 0x7fffu;   // v(t-1)
                unsigned g[8];
#pragma unroll
                for (int k = 0; k < 8; ++k) g[k] = ld_dev_u32(mbv + (k << 9) + tid);
                for (;;) {
                    unsigned bad = 0u;
#pragma unroll
                    for (int k = 0; k < 8; ++k)
                        if ((g[k] & 0x7fffu) != want) bad |= 1u << k;
                    if (!bad) break;
                    __builtin_amdgcn_s_sleep(1);
#pragma unroll
                    for (int k = 0; k < 8; ++k)
                        if (bad & (1u << k)) g[k] = ld_dev_u32(mbv + (k << 9) + tid);
                }
                unsigned fzb = 0x8000u;
#pragma unroll
                for (int k = 0; k < 8; ++k) {
                    vlh[(k << 9) + tid] = (unsigned short)(g[k] >> 16);
                    fzb &= g[k];
                }
                const bool allf = __all(fzb != 0u);
                if ((tid & 63) == 0) fb_lds[tid >> 6] = allf ? 1u : 0u;
            }
            __syncthreads();
            if ((t & 1) == 0) {
                // v(t-1)==v(t-3) bitwise everywhere -> remaining iterations
                // bit-identical; u32g/v32g already final. Exact skip.
                if ((fb_lds[0] & fb_lds[1] & fb_lds[2] & fb_lds[3] &
                     fb_lds[4] & fb_lds[5] & fb_lds[6] & fb_lds[7]) != 0u)
                    break;
            }
        }

        // ===== u-half compute: u = a / (Kh . v), matrix from registers =====
        {
            const uint4* V = (const uint4*)vlds;
            const uint4 a = V[g0], b = V[g0 + 64], c = V[g0 + 128], d = V[g0 + 192];
            float x0 = 0.f, x1 = 0.f, x2 = 0.f, x3 = 0.f;
            x0 = dot2(ku0.x, a.x, x0); x0 = dot2(ku0.y, a.y, x0);
            x0 = dot2(ku0.z, a.z, x0); x0 = dot2(ku0.w, a.w, x0);
            x1 = dot2(ku1.x, b.x, x1); x1 = dot2(ku1.y, b.y, x1);
            x1 = dot2(ku1.z, b.z, x1); x1 = dot2(ku1.w, b.w, x1);
            x2 = dot2(ku2.x, c.x, x2); x2 = dot2(ku2.y, c.y, x2);
            x2 = dot2(ku2.z, c.z, x2); x2 = dot2(ku2.w, c.w, x2);
            x3 = dot2(ku3.x, d.x, x3); x3 = dot2(ku3.y, d.y, x3);
            x3 = dot2(ku3.z, d.z, x3); x3 = dot2(ku3.w, d.w, x3);
            float acc = (x0 + x1) + (x2 + x3);
#pragma unroll
            for (int off = 32; off > 0; off >>= 1) acc += __shfl_down(acc, off, 64);
            if (lane == 0) part[w] = acc;
        }
        __syncthreads();
        if (tid < 8) {   // publish u(t): one self-validating u32 per row
            float r = A_MARG / (part[2 * tid] + part[2 * tid + 1]);
            u32g[bid * 8 + tid] = r;
            const unsigned val = (unsigned)__half_as_ushort(__float2half(r));
            st_dev_u32(mbu + bid * 8 + tid,
                       (val << 16) | ((unsigned)(2 * t + 1) & 0x7fffu));
        }

        // ===== v-half stage: u(t) rows {k*512+tid} -> LDS =====
        if (tid < 512) {
            const unsigned want = (unsigned)(2 * t + 1) & 0x7fffu;   // u(t)
            unsigned g[8];
#pragma unroll
            for (int k = 0; k < 8; ++k) g[k] = ld_dev_u32(mbu + (k << 9) + tid);
            for (;;) {
                unsigned bad = 0u;
#pragma unroll
                for (int k = 0; k < 8; ++k)
                    if ((g[k] & 0x7fffu) != want) bad |= 1u << k;
                if (!bad) break;
                __builtin_amdgcn_s_sleep(1);
#pragma unroll
                for (int k = 0; k < 8; ++k)
                    if (bad & (1u << k)) g[k] = ld_dev_u32(mbu + (k << 9) + tid);
            }
#pragma unroll
            for (int k = 0; k < 8; ++k)
                vlh[(k << 9) + tid] = (unsigned short)(g[k] >> 16);
        }
        __syncthreads();

        // ===== v-half compute: v = b / (KTh . u), matrix from registers =====
        {
            const uint4* V = (const uint4*)vlds;
            const uint4 a = V[g0], b = V[g0 + 64], c = V[g0 + 128], d = V[g0 + 192];
            float x0 = 0.f, x1 = 0.f, x2 = 0.f, x3 = 0.f;
            x0 = dot2(kv0.x, a.x, x0); x0 = dot2(kv0.y, a.y, x0);
            x0 = dot2(kv0.z, a.z, x0); x0 = dot2(kv0.w, a.w, x0);
            x1 = dot2(kv1.x, b.x, x1); x1 = dot2(kv1.y, b.y, x1);
            x1 = dot2(kv1.z, b.z, x1); x1 = dot2(kv1.w, b.w, x1);
            x2 = dot2(kv2.x, c.x, x2); x2 = dot2(kv2.y, c.y, x2);
            x2 = dot2(kv2.z, c.z, x2); x2 = dot2(kv2.w, c.w, x2);
            x3 = dot2(kv3.x, d.x, x3); x3 = dot2(kv3.y, d.y, x3);
            x3 = dot2(kv3.z, d.z, x3); x3 = dot2(kv3.w, d.w, x3);
            float acc = (x0 + x1) + (x2 + x3);
#pragma unroll
            for (int off = 32; off > 0; off >>= 1) acc += __shfl_down(acc, off, 64);
            if (lane == 0) part[w] = acc;
        }
        __syncthreads();
        if (tid < 8) {   // publish v(t) (+freeze bit from register hist)
            float r = B_MARG / (part[2 * tid] + part[2 * tid + 1]);
            v32g[bid * 8 + tid] = r;
            const unsigned val = (unsigned)__half_as_ushort(__float2half(r));
            unsigned ph = (unsigned)(2 * t + 2) & 0x7fffu;
            if (t & 1) {   // v(t) vs v(t-2), register-resident history
                if (val == histv) ph |= 0x8000u;
                histv = val;
            }
            st_dev_u32(mbv + bid * 8 + tid, (val << 16) | ph);
        }
    }
}

// ---------------------------------------------------------------------------
// Fallback per-iteration rowpasses (identical to R6; used only if the
// cooperative launch is rejected under graph capture).
// ---------------------------------------------------------------------------
__global__ void __launch_bounds__(1024, 8)
rowpass_u(const __half* __restrict__ Mat, const __half* __restrict__ w16_in,
          float* __restrict__ w32_out, __half* __restrict__ w16_out,
          unsigned* __restrict__ conv, unsigned* __restrict__ slot, int t) {
    if (ld_dev_u32(conv)) return;
    if ((t & 1) == 0) {
        if (ld_dev_u32(slot) == 0u) {
            if (threadIdx.x == 0) st_dev_u32(conv, 1u);
            return;
        }
    } else {
        if (blockIdx.x == 0 && threadIdx.x == 0) st_dev_u32(slot, 0u);
    }

    __shared__ __align__(16) __half vlds[MM];
    __shared__ float part[16];
    const int tid  = threadIdx.x;
    const int lane = tid & 63;
    const int w    = tid >> 6;
    const int rib  = w >> 1;
    const int hlf  = w & 1;
    const int i    = blockIdx.x * 8 + rib;
    const uint4* __restrict__ Mrow = (const uint4*)(Mat + (size_t)i * MM);
    const int g0 = hlf * 256 + lane;

    uint4 stg;
    if (tid < 512) stg = ((const uint4*)w16_in)[tid];
    const uint4 k0 = Mrow[g0];
    const uint4 k1 = Mrow[g0 + 64];
    const uint4 k2 = Mrow[g0 + 128];
    const uint4 k3 = Mrow[g0 + 192];
    if (tid < 512) ((uint4*)vlds)[tid] = stg;
    __syncthreads();

    const uint4* V = (const uint4*)vlds;
    const uint4 v0 = V[g0];
    const uint4 v1 = V[g0 + 64];
    const uint4 v2 = V[g0 + 128];
    const uint4 v3 = V[g0 + 192];

    float a0 = 0.f, a1 = 0.f, a2 = 0.f, a3 = 0.f;
    a0 = dot2(k0.x, v0.x, a0); a0 = dot2(k0.y, v0.y, a0);
    a0 = dot2(k0.z, v0.z, a0); a0 = dot2(k0.w, v0.w, a0);
    a1 = dot2(k1.x, v1.x, a1); a1 = dot2(k1.y, v1.y, a1);
    a1 = dot2(k1.z, v1.z, a1); a1 = dot2(k1.w, v1.w, a1);
    a2 = dot2(k2.x, v2.x, a2); a2 = dot2(k2.y, v2.y, a2);
    a2 = dot2(k2.z, v2.z, a2); a2 = dot2(k2.w, v2.w, a2);
    a3 = dot2(k3.x, v3.x, a3); a3 = dot2(k3.y, v3.y, a3);
    a3 = dot2(k3.z, v3.z, a3); a3 = dot2(k3.w, v3.w, a3);
    float acc = (a0 + a1) + (a2 + a3);

#pragma unroll
    for (int off = 32; off > 0; off >>= 1) acc += __shfl_down(acc, off, 64);
    if (lane == 0) part[w] = acc;
    __syncthreads();

    if (tid < 8) {
        const int row = blockIdx.x * 8 + tid;
        float r = A_MARG / (part[2 * tid] + part[2 * tid + 1]);
        w32_out[row] = r;
        w16_out[row] = __float2half(r);
    }
}

__global__ void __launch_bounds__(1024, 8)
rowpass_v(const __half* __restrict__ Mat, const __half* __restrict__ w16_in,
          float* __restrict__ w32_out, __half* __restrict__ w16_out,
          unsigned short* __restrict__ hist,
          unsigned* __restrict__ conv, unsigned* __restrict__ slot, int t) {
    if (ld_dev_u32(conv)) return;

    __shared__ __align__(16) __half vlds[MM];
    __shared__ float part[16];
    const int tid  = threadIdx.x;
    const int lane = tid & 63;
    const int w    = tid >> 6;
    const int rib  = w >> 1;
    const int hlf  = w & 1;
    const int i    = blockIdx.x * 8 + rib;
    const uint4* __restrict__ Mrow = (const uint4*)(Mat + (size_t)i * MM);
    const int g0 = hlf * 256 + lane;

    uint4 stg;
    if (tid < 512) stg = ((const uint4*)w16_in)[tid];
    const uint4 k0 = Mrow[g0];
    const uint4 k1 = Mrow[g0 + 64];
    const uint4 k2 = Mrow[g0 + 128];
    const uint4 k3 = Mrow[g0 + 192];
    if (tid < 512) ((uint4*)vlds)[tid] = stg;
    __syncthreads();

    const uint4* V = (const uint4*)vlds;
    const uint4 v0 = V[g0];
    const uint4 v1 = V[g0 + 64];
    const uint4 v2 = V[g0 + 128];
    const uint4 v3 = V[g0 + 192];

    float a0 = 0.f, a1 = 0.f, a2 = 0.f, a3 = 0.f;
    a0 = dot2(k0.x, v0.x, a0); a0 = dot2(k0.y, v0.y, a0);
    a0 = dot2(k0.z, v0.z, a0); a0 = dot2(k0.w, v0.w, a0);
    a1 = dot2(k1.x, v1.x, a1); a1 = dot2(k1.y, v1.y, a1);
    a1 = dot2(k1.z, v1.z, a1); a1 = dot2(k1.w, v1.w, a1);
    a2 = dot2(k2.x, v2.x, a2); a2 = dot2(k2.y, v2.y, a2);
    a2 = dot2(k2.z, v2.z, a2); a2 = dot2(k2.w, v2.w, a2);
    a3 = dot2(k3.x, v3.x, a3); a3 = dot2(k3.y, v3.y, a3);
    a3 = dot2(k3.z, v3.z, a3); a3 = dot2(k3.w, v3.w, a3);
    float acc = (a0 + a1) + (a2 + a3);

#pragma unroll
    for (int off = 32; off > 0; off >>= 1) acc += __shfl_down(acc, off, 64);
    if (lane == 0) part[w] = acc;
    __syncthreads();

    if (tid < 8) {
        const int row = blockIdx.x * 8 + tid;
        float r = B_MARG / (part[2 * tid] + part[2 * tid + 1]);
        w32_out[row] = r;
        const __half h = __float2half(r);
        if (t & 1) {
            const unsigned short bits = __half_as_ushort(h);
            const unsigned short old2 = ld_dev_u16(hist + row);
            if (old2 != bits) st_dev_u32(slot, 1u);
            st_dev_u16(hist + row, bits);
        }
        w16_out[row] = h;
    }
}

// ---------------------------------------------------------------------------
// gamma[i][j] = u[i] * exp(-||x_i-y_j||^2/reg) * v[j]   (exact fp32 K)
// grid: (16, 256), block 256
// ---------------------------------------------------------------------------
__global__ void epilogue(const float* __restrict__ x, const float* __restrict__ y,
                         const float* __restrict__ u, const float* __restrict__ v,
                         float* __restrict__ out) {
    const int tid = threadIdx.x;
    const int j   = blockIdx.x * 256 + tid;
    const int r0  = blockIdx.y * 16;

    float yv[DD];
    const float4* y4 = (const float4*)(y + (size_t)j * DD);
#pragma unroll
    for (int k = 0; k < DD / 4; ++k) {
        float4 t = y4[k];
        yv[4 * k + 0] = t.x; yv[4 * k + 1] = t.y;
        yv[4 * k + 2] = t.z; yv[4 * k + 3] = t.w;
    }

    __shared__ float xs[16 * DD];
    __shared__ float u_lds[16];
    xs[tid]       = x[(size_t)r0 * DD + tid];
    xs[tid + 256] = x[(size_t)r0 * DD + tid + 256];
    if (tid < 16) u_lds[tid] = u[r0 + tid];
    __syncthreads();

    const float vj = v[j];
#pragma unroll 4
    for (int ii = 0; ii < 16; ++ii) {
        float acc = 0.0f;
#pragma unroll
        for (int k = 0; k < DD; ++k) {
            float d = xs[ii * DD + k] - yv[k];
            acc = fmaf(d, d, acc);
        }
        out[(size_t)(r0 + ii) * MM + j] = u_lds[ii] * __expf(-acc * INV_REG) * vj;
    }
}

extern "C" void kernel_launch(void* const* d_in, const int* in_sizes, int n_in,
                              void* d_out, int out_size, void* d_ws, size_t ws_size,
                              hipStream_t stream) {
    const float* x = (const float*)d_in[0];
    const float* y = (const float*)d_in[1];
    __half*   Kh   = (__half*)d_ws;                    // 32 MB
    __half*   KTh  = Kh + (size_t)NN * MM;             // 32 MB
    float*    u32  = (float*)(KTh + (size_t)NN * MM);  // 16 KB
    float*    v32  = u32 + NN;                         // 16 KB
    __half*   u16  = (__half*)(v32 + MM);              // 8 KB (fallback)
    __half*   v16  = u16 + NN;                         // 8 KB (fallback)
    unsigned short* hist = (unsigned short*)(v16 + MM);// 8 KB (fallback; 0xAA-safe)
    unsigned* slot = (unsigned*)(hist + MM);           // 4 B (fallback)
    unsigned* conv = slot + 1;                         // 4 B (fallback)
    unsigned* mbu  = slot + 512;                       // 16 KB u row-mailbox
    unsigned* mbv  = mbu + NN;                         // 16 KB v row-mailbox
    float*    out  = (float*)d_out;

    compute_K_half<<<dim3(MM / 256, NN / 16), 256, 0, stream>>>(x, y, Kh, v16, conv, slot, mbu, mbv, 1);
    compute_K_half<<<dim3(NN / 256, MM / 16), 256, 0, stream>>>(y, x, KTh, v16, conv, slot, mbu, mbv, 0);

    {
        void* args[] = { &Kh, &KTh, &u32, &v32, &mbu, &mbv };
        hipError_t e = hipLaunchCooperativeKernel((const void*)sinkhorn_persist,
                                                  dim3(512), dim3(1024), args, 0, stream);
        if (e != hipSuccess) {
            (void)hipGetLastError();   // clear; fall back to per-iteration dispatches
            for (int t = 0; t < N_ITERS; ++t) {
                rowpass_u<<<NN / 8, 1024, 0, stream>>>(Kh,  v16, u32, u16, conv, slot, t);
                rowpass_v<<<MM / 8, 1024, 0, stream>>>(KTh, u16, v32, v16, hist, conv, slot, t);
            }
        }
    }

    epilogue<<<dim3(MM / 256, NN / 16), 256, 0, stream>>>(x, y, u32, v32, out);
}

// Round 10
// 539.409 us; speedup vs baseline: 1.8843x; 1.0691x over previous
//
#include <hip/hip_runtime.h>
#include <hip/hip_fp16.h>

// Sinkhorn OT: n=m=4096, d=32, reg=0.1, 100 iterations, uniform marginals.
// R15 = R14 (persistent kernel, matrix in VGPRs, fused val|phase row
// mailboxes) with the LAUNCH MECHANICS fixed:
//   - R9..R14 showed a constant ~100us overhead vs the dispatch-loop design
//     (total-persist ~178us vs R6's ~71us) that appeared exactly when we
//     adopted hipLaunchCooperativeKernel. The kernel uses NO cooperative
//     API -- its mailbox protocol only needs co-residency, which is
//     guaranteed by occupancy arithmetic: 1024thr=16 waves -> 2 blocks/CU
//     (32-wave cap) x 256 CU = 512 blocks; LDS 2x8.7KB << 160KB;
//     __launch_bounds__(1024,8) caps VGPR at 64. So: plain <<<512,1024>>>
//     launch. Early blocks spin in s_sleep until the grid fills (us-scale).
//   - the two K-build dispatches merged into one (grid.z selects direction).
// Persist kernel body is byte-identical to R14 (verified): one
// self-validating u32 (val16<<16|phase16) per row per half-pass, staging
// threads poll-load 8 rows each, freeze bit rides phase bit15, matrix rows
// register-resident (FETCH 46MB in R13 proved zero in-loop matrix traffic).
// Numerics bit-identical to R11..R14. absmax 2.384186e-07 expected.

#define NN 4096
#define MM 4096
#define DD 32
#define N_ITERS 100

static constexpr float INV_REG = 10.0f;
static constexpr float A_MARG  = 1.0f / 4096.0f;
static constexpr float B_MARG  = 1.0f / 4096.0f;

typedef _Float16 h2_t __attribute__((ext_vector_type(2)));

static __device__ __forceinline__ float dot2(unsigned a, unsigned b, float acc) {
#if __has_builtin(__builtin_amdgcn_fdot2)
    return __builtin_amdgcn_fdot2(__builtin_bit_cast(h2_t, a),
                                  __builtin_bit_cast(h2_t, b), acc, false);
#else
    float2 fa = __half22float2(*(const __half2*)&a);
    float2 fb = __half22float2(*(const __half2*)&b);
    acc = fmaf(fa.x, fb.x, acc);
    return fmaf(fa.y, fb.y, acc);
#endif
}

static __device__ __forceinline__ unsigned ld_dev_u32(const unsigned* p) {
    return __hip_atomic_load(p, __ATOMIC_RELAXED, __HIP_MEMORY_SCOPE_AGENT);
}
static __device__ __forceinline__ void st_dev_u32(unsigned* p, unsigned v) {
    __hip_atomic_store(p, v, __ATOMIC_RELAXED, __HIP_MEMORY_SCOPE_AGENT);
}

// ---------------------------------------------------------------------------
// One fused K-build dispatch. z=0: Kh[i][j]=exp(-||x_i-y_j||^2/reg) from
// (p=x, q=y); z=1: KTh from (p=y, q=x). z==0,by==0 also zeroes the row
// mailboxes (phase 0 = invalid; 0xAA ws poison never matches a wanted phase
// and is overwritten here anyway).
// grid: (16, 256, 2), block 256
// ---------------------------------------------------------------------------
__global__ void compute_K_half(const float* __restrict__ x, const float* __restrict__ y,
                               __half* __restrict__ Kh, __half* __restrict__ KTh,
                               unsigned* __restrict__ mbu, unsigned* __restrict__ mbv) {
    const int tid = threadIdx.x;
    const int j   = blockIdx.x * 256 + tid;
    const int r0  = blockIdx.y * 16;
    const int z   = blockIdx.z;
    const float* __restrict__ p = z ? y : x;
    const float* __restrict__ q = z ? x : y;
    __half* __restrict__ dst    = z ? KTh : Kh;

    if (z == 0 && blockIdx.y == 0) {
        mbu[j] = 0u;
        mbv[j] = 0u;
    }

    float qv[DD];
    const float4* q4 = (const float4*)(q + (size_t)j * DD);
#pragma unroll
    for (int k = 0; k < DD / 4; ++k) {
        float4 t = q4[k];
        qv[4 * k + 0] = t.x; qv[4 * k + 1] = t.y;
        qv[4 * k + 2] = t.z; qv[4 * k + 3] = t.w;
    }

    __shared__ float ps[16 * DD];
    ps[tid]       = p[(size_t)r0 * DD + tid];
    ps[tid + 256] = p[(size_t)r0 * DD + tid + 256];
    __syncthreads();

#pragma unroll 4
    for (int ii = 0; ii < 16; ++ii) {
        float acc = 0.0f;
#pragma unroll
        for (int k = 0; k < DD; ++k) {
            float d = ps[ii * DD + k] - qv[k];
            acc = fmaf(d, d, acc);
        }
        dst[(size_t)(r0 + ii) * MM + j] = __float2half(__expf(-acc * INV_REG));
    }
}

// ---------------------------------------------------------------------------
// Persistent kernel: all 100 iterations, fused val|phase row-mailboxes,
// matrix in VGPRs. 512 blocks x 1024 thr (16 waves), 2 waves per row,
// 4 fdot2 chains. Launched as a NORMAL kernel; co-residency by occupancy
// arithmetic (see header). Bit-identical accumulation order to R11..R14.
// ---------------------------------------------------------------------------
__global__ void __launch_bounds__(1024, 8)
sinkhorn_persist(const __half* __restrict__ Kh, const __half* __restrict__ KTh,
                 float* __restrict__ u32g, float* __restrict__ v32g,
                 unsigned* __restrict__ mbu, unsigned* __restrict__ mbv) {
    __shared__ __align__(16) __half vlds[MM];
    __shared__ float part[16];
    __shared__ unsigned fb_lds[8];
    const int tid  = threadIdx.x;
    const int lane = tid & 63;
    const int w    = tid >> 6;          // wave 0..15
    const int rib  = w >> 1;            // row-in-block 0..7
    const int hlf  = w & 1;             // half-row
    const int bid  = blockIdx.x;
    const int i    = bid * 8 + rib;
    const int g0   = hlf * 256 + lane;  // uint4 index into 512-uint4 row
    const uint4* __restrict__ MU = (const uint4*)(Kh  + (size_t)i * MM);
    const uint4* __restrict__ MV = (const uint4*)(KTh + (size_t)i * MM);
    unsigned short* __restrict__ vlh = (unsigned short*)vlds;

    // ---- matrix rows -> registers, ONCE (8 uint4 = 32 VGPR/lane) ----
    const uint4 ku0 = MU[g0], ku1 = MU[g0 + 64], ku2 = MU[g0 + 128], ku3 = MU[g0 + 192];
    const uint4 kv0 = MV[g0], kv1 = MV[g0 + 64], kv2 = MV[g0 + 128], kv3 = MV[g0 + 192];

    // freeze history: per-row prev-prev val16, register of thread tid<8.
    unsigned histv = 0x10000u;   // impossible 16-bit value

    for (int t = 0; t < N_ITERS; ++t) {
        // ===== u-half stage: v(t-1) rows {k*512+tid} -> LDS =====
        if (t == 0) {
            if (tid < 512) {
                const unsigned long long dv =
                    (unsigned long long)__half_as_ushort(__float2half(B_MARG)) *
                    0x0001000100010001ULL;
                ((unsigned long long*)vlds)[2 * tid]     = dv;
                ((unsigned long long*)vlds)[2 * tid + 1] = dv;
            }
            __syncthreads();
        } else {
            if (tid < 512) {
                const unsigned want = (unsigned)(2 * t) & 0x7fffu;   // v(t-1)
                unsigned g[8];
#pragma unroll
                for (int k = 0; k < 8; ++k) g[k] = ld_dev_u32(mbv + (k << 9) + tid);
                for (;;) {
                    unsigned bad = 0u;
#pragma unroll
                    for (int k = 0; k < 8; ++k)
                        if ((g[k] & 0x7fffu) != want) bad |= 1u << k;
                    if (!bad) break;
                    __builtin_amdgcn_s_sleep(1);
#pragma unroll
                    for (int k = 0; k < 8; ++k)
                        if (bad & (1u << k)) g[k] = ld_dev_u32(mbv + (k << 9) + tid);
                }
                unsigned fzb = 0x8000u;
#pragma unroll
                for (int k = 0; k < 8; ++k) {
                    vlh[(k << 9) + tid] = (unsigned short)(g[k] >> 16);
                    fzb &= g[k];
                }
                const bool allf = __all(fzb != 0u);
                if ((tid & 63) == 0) fb_lds[tid >> 6] = allf ? 1u : 0u;
            }
            __syncthreads();
            if ((t & 1) == 0) {
                // v(t-1)==v(t-3) bitwise everywhere -> remaining iterations
                // bit-identical; u32g/v32g already final. Exact skip.
                if ((fb_lds[0] & fb_lds[1] & fb_lds[2] & fb_lds[3] &
                     fb_lds[4] & fb_lds[5] & fb_lds[6] & fb_lds[7]) != 0u)
                    break;
            }
        }

        // ===== u-half compute: u = a / (Kh . v), matrix from registers =====
        {
            const uint4* V = (const uint4*)vlds;
            const uint4 a = V[g0], b = V[g0 + 64], c = V[g0 + 128], d = V[g0 + 192];
            float x0 = 0.f, x1 = 0.f, x2 = 0.f, x3 = 0.f;
            x0 = dot2(ku0.x, a.x, x0); x0 = dot2(ku0.y, a.y, x0);
            x0 = dot2(ku0.z, a.z, x0); x0 = dot2(ku0.w, a.w, x0);
            x1 = dot2(ku1.x, b.x, x1); x1 = dot2(ku1.y, b.y, x1);
            x1 = dot2(ku1.z, b.z, x1); x1 = dot2(ku1.w, b.w, x1);
            x2 = dot2(ku2.x, c.x, x2); x2 = dot2(ku2.y, c.y, x2);
            x2 = dot2(ku2.z, c.z, x2); x2 = dot2(ku2.w, c.w, x2);
            x3 = dot2(ku3.x, d.x, x3); x3 = dot2(ku3.y, d.y, x3);
            x3 = dot2(ku3.z, d.z, x3); x3 = dot2(ku3.w, d.w, x3);
            float acc = (x0 + x1) + (x2 + x3);
#pragma unroll
            for (int off = 32; off > 0; off >>= 1) acc += __shfl_down(acc, off, 64);
            if (lane == 0) part[w] = acc;
        }
        __syncthreads();
        if (tid < 8) {   // publish u(t): one self-validating u32 per row
            float r = A_MARG / (part[2 * tid] + part[2 * tid + 1]);
            u32g[bid * 8 + tid] = r;
            const unsigned val = (unsigned)__half_as_ushort(__float2half(r));
            st_dev_u32(mbu + bid * 8 + tid,
                       (val << 16) | ((unsigned)(2 * t + 1) & 0x7fffu));
        }

        // ===== v-half stage: u(t) rows {k*512+tid} -> LDS =====
        if (tid < 512) {
            const unsigned want = (unsigned)(2 * t + 1) & 0x7fffu;   // u(t)
            unsigned g[8];
#pragma unroll
            for (int k = 0; k < 8; ++k) g[k] = ld_dev_u32(mbu + (k << 9) + tid);
            for (;;) {
                unsigned bad = 0u;
#pragma unroll
                for (int k = 0; k < 8; ++k)
                    if ((g[k] & 0x7fffu) != want) bad |= 1u << k;
                if (!bad) break;
                __builtin_amdgcn_s_sleep(1);
#pragma unroll
                for (int k = 0; k < 8; ++k)
                    if (bad & (1u << k)) g[k] = ld_dev_u32(mbu + (k << 9) + tid);
            }
#pragma unroll
            for (int k = 0; k < 8; ++k)
                vlh[(k << 9) + tid] = (unsigned short)(g[k] >> 16);
        }
        __syncthreads();

        // ===== v-half compute: v = b / (KTh . u), matrix from registers =====
        {
            const uint4* V = (const uint4*)vlds;
            const uint4 a = V[g0], b = V[g0 + 64], c = V[g0 + 128], d = V[g0 + 192];
            float x0 = 0.f, x1 = 0.f, x2 = 0.f, x3 = 0.f;
            x0 = dot2(kv0.x, a.x, x0); x0 = dot2(kv0.y, a.y, x0);
            x0 = dot2(kv0.z, a.z, x0); x0 = dot2(kv0.w, a.w, x0);
            x1 = dot2(kv1.x, b.x, x1); x1 = dot2(kv1.y, b.y, x1);
            x1 = dot2(kv1.z, b.z, x1); x1 = dot2(kv1.w, b.w, x1);
            x2 = dot2(kv2.x, c.x, x2); x2 = dot2(kv2.y, c.y, x2);
            x2 = dot2(kv2.z, c.z, x2); x2 = dot2(kv2.w, c.w, x2);
            x3 = dot2(kv3.x, d.x, x3); x3 = dot2(kv3.y, d.y, x3);
            x3 = dot2(kv3.z, d.z, x3); x3 = dot2(kv3.w, d.w, x3);
            float acc = (x0 + x1) + (x2 + x3);
#pragma unroll
            for (int off = 32; off > 0; off >>= 1) acc += __shfl_down(acc, off, 64);
            if (lane == 0) part[w] = acc;
        }
        __syncthreads();
        if (tid < 8) {   // publish v(t) (+freeze bit from register hist)
            float r = B_MARG / (part[2 * tid] + part[2 * tid + 1]);
            v32g[bid * 8 + tid] = r;
            const unsigned val = (unsigned)__half_as_ushort(__float2half(r));
            unsigned ph = (unsigned)(2 * t + 2) & 0x7fffu;
            if (t & 1) {   // v(t) vs v(t-2), register-resident history
                if (val == histv) ph |= 0x8000u;
                histv = val;
            }
            st_dev_u32(mbv + bid * 8 + tid, (val << 16) | ph);
        }
    }
}

// ---------------------------------------------------------------------------
// gamma[i][j] = u[i] * exp(-||x_i-y_j||^2/reg) * v[j]   (exact fp32 K)
// grid: (16, 256), block 256
// ---------------------------------------------------------------------------
__global__ void epilogue(const float* __restrict__ x, const float* __restrict__ y,
                         const float* __restrict__ u, const float* __restrict__ v,
                         float* __restrict__ out) {
    const int tid = threadIdx.x;
    const int j   = blockIdx.x * 256 + tid;
    const int r0  = blockIdx.y * 16;

    float yv[DD];
    const float4* y4 = (const float4*)(y + (size_t)j * DD);
#pragma unroll
    for (int k = 0; k < DD / 4; ++k) {
        float4 t = y4[k];
        yv[4 * k + 0] = t.x; yv[4 * k + 1] = t.y;
        yv[4 * k + 2] = t.z; yv[4 * k + 3] = t.w;
    }

    __shared__ float xs[16 * DD];
    __shared__ float u_lds[16];
    xs[tid]       = x[(size_t)r0 * DD + tid];
    xs[tid + 256] = x[(size_t)r0 * DD + tid + 256];
    if (tid < 16) u_lds[tid] = u[r0 + tid];
    __syncthreads();

    const float vj = v[j];
#pragma unroll 4
    for (int ii = 0; ii < 16; ++ii) {
        float acc = 0.0f;
#pragma unroll
        for (int k = 0; k < DD; ++k) {
            float d = xs[ii * DD + k] - yv[k];
            acc = fmaf(d, d, acc);
        }
        out[(size_t)(r0 + ii) * MM + j] = u_lds[ii] * __expf(-acc * INV_REG) * vj;
    }
}

extern "C" void kernel_launch(void* const* d_in, const int* in_sizes, int n_in,
                              void* d_out, int out_size, void* d_ws, size_t ws_size,
                              hipStream_t stream) {
    const float* x = (const float*)d_in[0];
    const float* y = (const float*)d_in[1];
    __half*   Kh   = (__half*)d_ws;                    // 32 MB
    __half*   KTh  = Kh + (size_t)NN * MM;             // 32 MB
    float*    u32  = (float*)(KTh + (size_t)NN * MM);  // 16 KB
    float*    v32  = u32 + NN;                         // 16 KB
    unsigned* mbu  = (unsigned*)(v32 + MM);            // 16 KB u row-mailbox
    unsigned* mbv  = mbu + NN;                         // 16 KB v row-mailbox
    float*    out  = (float*)d_out;

    compute_K_half<<<dim3(16, 256, 2), 256, 0, stream>>>(x, y, Kh, KTh, mbu, mbv);

    // Normal launch: co-residency of all 512 blocks guaranteed by occupancy
    // (16 waves/block, 32-wave/CU cap -> exactly 2 blocks/CU x 256 CU; LDS
    // 2x8.7KB << 160KB; launch_bounds(1024,8) caps VGPR at 64).
    sinkhorn_persist<<<512, 1024, 0, stream>>>(Kh, KTh, u32, v32, mbu, mbv);

    epilogue<<<dim3(MM / 256, NN / 16), 256, 0, stream>>>(x, y, u32, v32, out);
}